// Round 1
// baseline (285.663 us; speedup 1.0000x reference)
//
#include <hip/hip_runtime.h>
#include <math.h>

// Problem constants (fixed by setup_inputs)
#define BB   16
#define HW   65536          // 256*256
#define NPIX (BB * HW)      // 1,048,576

// ws layout (bytes)
#define HIST1_OFF 0ull            // 16*65536*4 = 4 MB
#define HIST2_OFF (4ull << 20)    // 4 MB
#define UARR_OFF  (8ull << 20)    // 4 MB
#define CLSL_OFF  (12ull << 20)   // 4 MB
#define CLSW_OFF  (16ull << 20)   // 4 MB
#define STATS_OFF (20ull << 20)

// stats indices (u32 view unless noted)
#define S_NPOS   0    // [16] per-image pos count
#define S_NNEG   16   // [16] per-image neg count
#define S_BUCKET 32   // [16] hi-16 bucket (0xFFFFFFFF = shortcut/skip)
#define S_RANK   48   // [16] rank within bucket
#define S_THR    64   // [16] final u-threshold (select: u <= thr)
#define S_NSEL   80   // total selected-neg count
#define F_SUMWL  96   // float: sum(cls_loss * (w + sel))
#define F_S1     97   // float: link sums
#define F_M1     98
#define F_S0     99
#define F_M0     100

// monotone unsigned mapping of float bits (ascending float -> ascending uint)
__device__ __forceinline__ unsigned fmap(float x) {
  unsigned b = __float_as_uint(x);
  return (b & 0x80000000u) ? ~b : (b | 0x80000000u);
}

// Pass A: read everything once; per-pixel cls records, hi-16 histogram of d
// over neg pixels, per-image pos/neg counts, global link-loss sums.
__global__ void kA(const float* __restrict__ target, const float* __restrict__ logits,
                   unsigned* __restrict__ hist1, unsigned* __restrict__ uarr,
                   float* __restrict__ clsl, float* __restrict__ clsw,
                   unsigned* __restrict__ stats) {
  int i = blockIdx.x * 256 + threadIdx.x;
  int b = i >> 16;
  int hw = i & 65535;

  const float2* t2 = (const float2*)(target + (size_t)i * 10);
  float2 p0 = t2[0], p1 = t2[1], p2 = t2[2], p3 = t2[3], p4 = t2[4];
  float label = p0.x;
  bool pos = label > 0.f;
  bool neg = label == 0.f;

  const float* lg = logits + (size_t)b * 10 * HW + hw;
  float l0 = lg[0];
  float l1 = lg[HW];
  float d = l0 - l1;
  float lse = fmaxf(l0, l1) + log1pf(expf(-fabsf(d)));
  clsl[i] = lse - (pos ? l1 : l0);   // pixel_cls_loss
  clsw[i] = p0.y;                    // pixel_cls_weights

  unsigned u = fmap(d);              // score = sigmoid(d) is monotone in d
  uarr[i] = neg ? u : 0xFFFFFFFFu;   // finite d never maps to 0xFFFFFFFF
  if (neg) atomicAdd(&hist1[(size_t)b * 65536 + (u >> 16)], 1u);

  // link loss contributions (threshold-independent)
  float ll[4] = {p1.x, p1.y, p2.x, p2.y};
  float lw[4] = {p3.x, p3.y, p4.x, p4.y};
  float s1 = 0.f, m1 = 0.f, s0 = 0.f, m0 = 0.f;
#pragma unroll
  for (int n = 0; n < 4; n++) {
    float a = lg[(2 + n) * HW];      // class-0 logit
    float c = lg[(6 + n) * HW];      // class-1 logit
    float lse2 = fmaxf(a, c) + log1pf(expf(-fabsf(a - c)));
    int lab = (int)ll[n];
    float ce = lse2 - (lab ? c : a);
    float w = lw[n];
    if (lab == 1)      { m1 += w; s1 += w * ce; }
    else if (lab == 0) { m0 += w; s0 += w * ce; }
  }

  // block reduction of 6 quantities, one atomic each per block
  float vals[6] = {pos ? 1.f : 0.f, neg ? 1.f : 0.f, s1, m1, s0, m0};
  __shared__ float red[6][4];
  int wave = threadIdx.x >> 6, lane = threadIdx.x & 63;
#pragma unroll
  for (int q = 0; q < 6; q++) {
    float v = vals[q];
    for (int o = 32; o; o >>= 1) v += __shfl_down(v, o, 64);
    if (lane == 0) red[q][wave] = v;
  }
  __syncthreads();
  if (threadIdx.x < 6) {
    int q = threadIdx.x;
    float v = red[q][0] + red[q][1] + red[q][2] + red[q][3];
    int img = blockIdx.x >> 8;       // 256 blocks per image
    if (q == 0)      atomicAdd(&stats[S_NPOS + img], (unsigned)(v + 0.5f));
    else if (q == 1) atomicAdd(&stats[S_NNEG + img], (unsigned)(v + 0.5f));
    else             atomicAdd(((float*)stats) + (F_S1 + (q - 2)), v);
  }
}

// Scan a 65536-bin histogram for the k-th element. phase 0: hi-16 (k from
// OHEM counts, with select-all shortcut). phase 1: lo-16 (k = stored rank).
__global__ void kScan(const unsigned* __restrict__ hist, unsigned* __restrict__ stats,
                      int phase) {
  int b = blockIdx.x;
  unsigned k;
  if (phase == 0) {
    unsigned npos = stats[S_NPOS + b], nneg = stats[S_NNEG + b];
    unsigned kk = min(3u * npos, nneg);
    if (npos == 0u || kk == 0u || kk >= nneg) {
      // use_all OR k==n_neg (thr = max neg score): select all negatives.
      if (threadIdx.x == 0) { stats[S_THR + b] = 0xFFFFFFFEu; stats[S_BUCKET + b] = 0xFFFFFFFFu; }
      return;
    }
    k = kk;
  } else {
    if (stats[S_BUCKET + b] == 0xFFFFFFFFu) return;
    k = stats[S_RANK + b];
  }
  __shared__ unsigned part[256];
  __shared__ unsigned pref[256];
  const unsigned* h = hist + (size_t)b * 65536 + (size_t)threadIdx.x * 256;
  unsigned p = 0;
  for (int j = 0; j < 256; j++) p += h[j];
  part[threadIdx.x] = p;
  __syncthreads();
  if (threadIdx.x == 0) {
    unsigned c = 0;
    for (int t = 0; t < 256; t++) { pref[t] = c; c += part[t]; }
  }
  __syncthreads();
  unsigned before = pref[threadIdx.x];
  if (before < k && k <= before + part[threadIdx.x]) {   // exactly one thread
    unsigned cum = before;
    for (int j = 0; j < 256; j++) {
      unsigned cnt = h[j];
      if (k <= cum + cnt) {
        unsigned bin = (unsigned)threadIdx.x * 256u + (unsigned)j;
        if (phase == 0) { stats[S_BUCKET + b] = bin; stats[S_RANK + b] = k - cum; }
        else            { stats[S_THR + b] = (stats[S_BUCKET + b] << 16) | bin; }
        break;
      }
      cum += cnt;
    }
  }
}

// lo-16 histogram within the selected bucket (skipped entirely via per-image flag)
__global__ void kC(const unsigned* __restrict__ uarr, unsigned* __restrict__ hist2,
                   const unsigned* __restrict__ stats) {
  int b = blockIdx.x >> 8;
  unsigned bk = stats[S_BUCKET + b];
  if (bk == 0xFFFFFFFFu) return;
  int i = blockIdx.x * 256 + threadIdx.x;
  unsigned u = uarr[i];
  if (u != 0xFFFFFFFFu && (u >> 16) == bk)
    atomicAdd(&hist2[(size_t)b * 65536 + (u & 0xFFFFu)], 1u);
}

// Final per-pixel pass: selection + weighted cls-loss sums.
__global__ void kB(const unsigned* __restrict__ uarr, const float* __restrict__ clsl,
                   const float* __restrict__ clsw, unsigned* __restrict__ stats) {
  int i = blockIdx.x * 256 + threadIdx.x;
  int b = i >> 16;
  unsigned thr = stats[S_THR + b];
  unsigned u = uarr[i];
  float sel = (u <= thr) ? 1.f : 0.f;
  float contrib = clsl[i] * (clsw[i] + sel);
  for (int o = 32; o; o >>= 1) {
    contrib += __shfl_down(contrib, o, 64);
    sel     += __shfl_down(sel, o, 64);
  }
  __shared__ float redc[4], reds[4];
  int wave = threadIdx.x >> 6, lane = threadIdx.x & 63;
  if (lane == 0) { redc[wave] = contrib; reds[wave] = sel; }
  __syncthreads();
  if (threadIdx.x == 0) {
    float c = redc[0] + redc[1] + redc[2] + redc[3];
    unsigned s = (unsigned)(reds[0] + reds[1] + reds[2] + reds[3] + 0.5f);
    atomicAdd(((float*)stats) + F_SUMWL, c);
    atomicAdd(&stats[S_NSEL], s);
  }
}

__global__ void kFinal(const unsigned* __restrict__ stats, float* __restrict__ out) {
  if (threadIdx.x == 0) {
    unsigned npos = 0;
    for (int b = 0; b < BB; b++) npos += stats[S_NPOS + b];
    unsigned nsel = stats[S_NSEL];
    const float* f = (const float*)stats;
    float cls = 2.f * f[F_SUMWL] / (float)(npos + nsel);
    float link = 0.f;
    if (npos != 0u) link = f[F_S1] / f[F_M1] + f[F_S0] / f[F_M0];
    out[0] = cls;
    out[1] = link;
  }
}

extern "C" void kernel_launch(void* const* d_in, const int* in_sizes, int n_in,
                              void* d_out, int out_size, void* d_ws, size_t ws_size,
                              hipStream_t stream) {
  const float* target = (const float*)d_in[0];   // (16,256,256,10)
  const float* logits = (const float*)d_in[1];   // (16,10,256,256)
  float* out = (float*)d_out;                    // [cls_loss*2, link_loss]
  char* ws = (char*)d_ws;

  unsigned* hist1 = (unsigned*)(ws + HIST1_OFF);
  unsigned* hist2 = (unsigned*)(ws + HIST2_OFF);
  unsigned* uarr  = (unsigned*)(ws + UARR_OFF);
  float*    clsl  = (float*)(ws + CLSL_OFF);
  float*    clsw  = (float*)(ws + CLSW_OFF);
  unsigned* stats = (unsigned*)(ws + STATS_OFF);

  // ws is re-poisoned to 0xAA before every launch: zero what we accumulate into.
  hipMemsetAsync(hist1, 0, 8ull << 20, stream);   // hist1 + hist2 (contiguous)
  hipMemsetAsync(stats, 0, 512, stream);

  dim3 grid(NPIX / 256), block(256);
  kA<<<grid, block, 0, stream>>>(target, logits, hist1, uarr, clsl, clsw, stats);
  kScan<<<BB, 256, 0, stream>>>(hist1, stats, 0);
  kC<<<grid, block, 0, stream>>>(uarr, hist2, stats);
  kScan<<<BB, 256, 0, stream>>>(hist2, stats, 1);
  kB<<<grid, block, 0, stream>>>(uarr, clsl, clsw, stats);
  kFinal<<<1, 64, 0, stream>>>(stats, out);
}

// Round 2
// 160.008 us; speedup vs baseline: 1.7853x; 1.7853x over previous
//
#include <hip/hip_runtime.h>
#include <math.h>

// Problem constants (fixed by setup_inputs)
#define BB   16
#define HW   65536          // 256*256
#define NPIX (BB * HW)      // 1,048,576
#define NBLK (NPIX / 256)   // 4096 blocks in the per-pixel kernels

// ws layout (bytes)
#define HIST1_OFF 0ull            // 16*65536*4 = 4 MB
#define HIST2_OFF (4ull << 20)    // 4 MB
#define UARR_OFF  (8ull << 20)    // 4 MB
#define CLSL_OFF  (12ull << 20)   // 4 MB
#define CLSW_OFF  (16ull << 20)   // 4 MB
// 8 partial arrays of NBLK 4-byte entries (plain stores, NO contended atomics):
//  slot 0: per-block pos count (u32)   slot 1: per-block neg count (u32)
//  slot 2..5: per-block s1,m1,s0,m0 (float)
//  slot 6: per-block cls contrib (float)   slot 7: per-block sel count (u32)
#define PART_OFF  (20ull << 20)
#define STATS_OFF (PART_OFF + 8ull * NBLK * 4ull)

// stats indices (u32 view unless noted) — every slot is WRITTEN (stored, not
// accumulated), so stats needs no memset.
#define S_NPOS   0    // [16]
#define S_NNEG   16   // [16]
#define S_BUCKET 32   // [16] hi-16 bucket (0xFFFFFFFF = shortcut/skip)
#define S_RANK   48   // [16]
#define S_THR    64   // [16] select: u <= thr
#define F_S1     80   // float link sums
#define F_M1     81
#define F_S0     82
#define F_M0     83

// monotone unsigned mapping of float bits (ascending float -> ascending uint)
__device__ __forceinline__ unsigned fmap(float x) {
  unsigned b = __float_as_uint(x);
  return (b & 0x80000000u) ? ~b : (b | 0x80000000u);
}

// Pass A: read both inputs once; per-pixel records, hi-16 histogram (spread
// u32 atomics only), per-block partials via plain stores.
__global__ void kA(const float* __restrict__ target, const float* __restrict__ logits,
                   unsigned* __restrict__ hist1, unsigned* __restrict__ uarr,
                   float* __restrict__ clsl, float* __restrict__ clsw,
                   unsigned* __restrict__ part) {
  int i = blockIdx.x * 256 + threadIdx.x;
  int b = i >> 16;
  int hw = i & 65535;

  const float2* t2 = (const float2*)(target + (size_t)i * 10);
  float2 p0 = t2[0], p1 = t2[1], p2 = t2[2], p3 = t2[3], p4 = t2[4];
  bool pos = p0.x > 0.f;
  bool neg = p0.x == 0.f;

  const float* lg = logits + (size_t)b * 10 * HW + hw;
  float l0 = lg[0];
  float l1 = lg[HW];
  float d = l0 - l1;
  float lse = fmaxf(l0, l1) + log1pf(expf(-fabsf(d)));
  clsl[i] = lse - (pos ? l1 : l0);   // pixel_cls_loss
  clsw[i] = p0.y;                    // pixel_cls_weights

  unsigned u = fmap(d);              // score = sigmoid(d) is monotone in d
  uarr[i] = neg ? u : 0xFFFFFFFFu;   // finite d never maps to 0xFFFFFFFF
  if (neg) atomicAdd(&hist1[(size_t)b * 65536 + (u >> 16)], 1u);  // spread u32: fast

  // link loss contributions (threshold-independent); labels are {0,1}
  float ll[4] = {p1.x, p1.y, p2.x, p2.y};
  float lw[4] = {p3.x, p3.y, p4.x, p4.y};
  float s1 = 0.f, m1 = 0.f, s0 = 0.f, m0 = 0.f;
#pragma unroll
  for (int n = 0; n < 4; n++) {
    float a = lg[(2 + n) * HW];      // class-0 logit
    float c = lg[(6 + n) * HW];      // class-1 logit
    float lse2 = fmaxf(a, c) + log1pf(expf(-fabsf(a - c)));
    int lab = (int)ll[n];
    float ce = lse2 - (lab ? c : a);
    float w = lw[n];
    if (lab) { m1 += w; s1 += w * ce; }
    else     { m0 += w; s0 += w * ce; }
  }

  int lane = threadIdx.x & 63, wave = threadIdx.x >> 6;
  unsigned long long bp = __ballot(pos), bn = __ballot(neg);
  __shared__ unsigned cpos[4], cneg[4];
  __shared__ float red[4][4];
  if (lane == 0) { cpos[wave] = __popcll(bp); cneg[wave] = __popcll(bn); }
  float v[4] = {s1, m1, s0, m0};
#pragma unroll
  for (int q = 0; q < 4; q++) {
    float x = v[q];
    for (int o = 32; o; o >>= 1) x += __shfl_down(x, o, 64);
    if (lane == 0) red[q][wave] = x;
  }
  __syncthreads();
  if (threadIdx.x == 0) {
    part[0 * NBLK + blockIdx.x] = cpos[0] + cpos[1] + cpos[2] + cpos[3];
    part[1 * NBLK + blockIdx.x] = cneg[0] + cneg[1] + cneg[2] + cneg[3];
  }
  if (threadIdx.x < 4) {
    int q = threadIdx.x;
    ((float*)part)[(2 + q) * NBLK + blockIdx.x] = red[q][0] + red[q][1] + red[q][2] + red[q][3];
  }
}

// Blocks 0-15: reduce image b's 256 count-partials, then hi-16 radix scan.
// Blocks 16-19: reduce one 4096-entry link-sum partial array each.
__global__ void kRedScan1(const unsigned* __restrict__ part, const unsigned* __restrict__ hist1,
                          unsigned* __restrict__ stats) {
  int lane = threadIdx.x & 63, wave = threadIdx.x >> 6;
  if (blockIdx.x >= 16) {
    int q = blockIdx.x - 16;
    const float* p = (const float*)part + (size_t)(2 + q) * NBLK;
    float s = 0.f;
    for (int t = threadIdx.x; t < NBLK; t += 256) s += p[t];
    for (int o = 32; o; o >>= 1) s += __shfl_down(s, o, 64);
    __shared__ float r[4];
    if (lane == 0) r[wave] = s;
    __syncthreads();
    if (threadIdx.x == 0) ((float*)stats)[F_S1 + q] = r[0] + r[1] + r[2] + r[3];
    return;
  }
  int b = blockIdx.x;
  unsigned cp = part[0 * NBLK + b * 256 + threadIdx.x];
  unsigned cn = part[1 * NBLK + b * 256 + threadIdx.x];
  for (int o = 32; o; o >>= 1) { cp += __shfl_down(cp, o, 64); cn += __shfl_down(cn, o, 64); }
  __shared__ unsigned rp[4], rn[4];
  __shared__ unsigned snpos, snneg;
  if (lane == 0) { rp[wave] = cp; rn[wave] = cn; }
  __syncthreads();
  if (threadIdx.x == 0) {
    snpos = rp[0] + rp[1] + rp[2] + rp[3];
    snneg = rn[0] + rn[1] + rn[2] + rn[3];
    stats[S_NPOS + b] = snpos;
    stats[S_NNEG + b] = snneg;
  }
  __syncthreads();
  unsigned npos = snpos, nneg = snneg;
  unsigned k = min(3u * npos, nneg);
  if (npos == 0u || k == 0u || k >= nneg) {
    // use_all OR k==n_neg: select all negatives (non-neg pixels carry 0xFFFFFFFF).
    if (threadIdx.x == 0) { stats[S_THR + b] = 0xFFFFFFFEu; stats[S_BUCKET + b] = 0xFFFFFFFFu; }
    return;
  }
  __shared__ unsigned partl[256], pref[256];
  const unsigned* h = hist1 + (size_t)b * 65536 + (size_t)threadIdx.x * 256;
  unsigned p = 0;
  for (int j = 0; j < 256; j++) p += h[j];
  partl[threadIdx.x] = p;
  __syncthreads();
  if (threadIdx.x == 0) {
    unsigned c = 0;
    for (int t = 0; t < 256; t++) { pref[t] = c; c += partl[t]; }
  }
  __syncthreads();
  unsigned before = pref[threadIdx.x];
  if (before < k && k <= before + partl[threadIdx.x]) {   // exactly one thread
    unsigned cum = before;
    for (int j = 0; j < 256; j++) {
      unsigned cnt = h[j];
      if (k <= cum + cnt) {
        stats[S_BUCKET + b] = (unsigned)threadIdx.x * 256u + (unsigned)j;
        stats[S_RANK + b] = k - cum;
        break;
      }
      cum += cnt;
    }
  }
}

// lo-16 histogram within the selected bucket (skipped per-image via flag)
__global__ void kC(const unsigned* __restrict__ uarr, unsigned* __restrict__ hist2,
                   const unsigned* __restrict__ stats) {
  int b = blockIdx.x >> 8;
  unsigned bk = stats[S_BUCKET + b];
  if (bk == 0xFFFFFFFFu) return;
  int i = blockIdx.x * 256 + threadIdx.x;
  unsigned u = uarr[i];
  if (u != 0xFFFFFFFFu && (u >> 16) == bk)
    atomicAdd(&hist2[(size_t)b * 65536 + (u & 0xFFFFu)], 1u);
}

// lo-16 scan within the chosen bucket -> final threshold
__global__ void kScan2(const unsigned* __restrict__ hist2, unsigned* __restrict__ stats) {
  int b = blockIdx.x;
  unsigned bucket = stats[S_BUCKET + b];
  if (bucket == 0xFFFFFFFFu) return;
  unsigned k = stats[S_RANK + b];
  __shared__ unsigned partl[256], pref[256];
  const unsigned* h = hist2 + (size_t)b * 65536 + (size_t)threadIdx.x * 256;
  unsigned p = 0;
  for (int j = 0; j < 256; j++) p += h[j];
  partl[threadIdx.x] = p;
  __syncthreads();
  if (threadIdx.x == 0) {
    unsigned c = 0;
    for (int t = 0; t < 256; t++) { pref[t] = c; c += partl[t]; }
  }
  __syncthreads();
  unsigned before = pref[threadIdx.x];
  if (before < k && k <= before + partl[threadIdx.x]) {
    unsigned cum = before;
    for (int j = 0; j < 256; j++) {
      unsigned cnt = h[j];
      if (k <= cum + cnt) {
        stats[S_THR + b] = (bucket << 16) | ((unsigned)threadIdx.x * 256u + (unsigned)j);
        break;
      }
      cum += cnt;
    }
  }
}

// Final per-pixel pass: selection + weighted cls-loss; per-block partial STORES.
__global__ void kB(const unsigned* __restrict__ uarr, const float* __restrict__ clsl,
                   const float* __restrict__ clsw, const unsigned* __restrict__ stats,
                   unsigned* __restrict__ part) {
  int i = blockIdx.x * 256 + threadIdx.x;
  int b = i >> 16;
  unsigned thr = stats[S_THR + b];
  unsigned u = uarr[i];
  bool sel = (u <= thr);
  float contrib = clsl[i] * (clsw[i] + (sel ? 1.f : 0.f));
  unsigned long long bs = __ballot(sel);
  for (int o = 32; o; o >>= 1) contrib += __shfl_down(contrib, o, 64);
  __shared__ float rc[4];
  __shared__ unsigned rs[4];
  int lane = threadIdx.x & 63, wave = threadIdx.x >> 6;
  if (lane == 0) { rc[wave] = contrib; rs[wave] = __popcll(bs); }
  __syncthreads();
  if (threadIdx.x == 0) {
    ((float*)part)[6 * NBLK + blockIdx.x] = rc[0] + rc[1] + rc[2] + rc[3];
    part[7 * NBLK + blockIdx.x] = rs[0] + rs[1] + rs[2] + rs[3];
  }
}

// Reduce kB's 4096 partials + assemble both outputs. One block.
__global__ void kFinal(const unsigned* __restrict__ part, const unsigned* __restrict__ stats,
                       float* __restrict__ out) {
  const float* pc = (const float*)part + 6ull * NBLK;
  const unsigned* ps = part + 7ull * NBLK;
  float c = 0.f;
  unsigned s = 0;
  for (int t = threadIdx.x; t < NBLK; t += 256) { c += pc[t]; s += ps[t]; }
  for (int o = 32; o; o >>= 1) { c += __shfl_down(c, o, 64); s += __shfl_down(s, o, 64); }
  __shared__ float rc[4];
  __shared__ unsigned rs[4];
  int lane = threadIdx.x & 63, wave = threadIdx.x >> 6;
  if (lane == 0) { rc[wave] = c; rs[wave] = s; }
  __syncthreads();
  if (threadIdx.x == 0) {
    float cs = rc[0] + rc[1] + rc[2] + rc[3];
    unsigned nsel = rs[0] + rs[1] + rs[2] + rs[3];
    unsigned npos = 0;
    for (int b = 0; b < BB; b++) npos += stats[S_NPOS + b];
    const float* f = (const float*)stats;
    out[0] = 2.f * cs / (float)(npos + nsel);
    out[1] = (npos != 0u) ? (f[F_S1] / f[F_M1] + f[F_S0] / f[F_M0]) : 0.f;
  }
}

extern "C" void kernel_launch(void* const* d_in, const int* in_sizes, int n_in,
                              void* d_out, int out_size, void* d_ws, size_t ws_size,
                              hipStream_t stream) {
  const float* target = (const float*)d_in[0];   // (16,256,256,10)
  const float* logits = (const float*)d_in[1];   // (16,10,256,256)
  float* out = (float*)d_out;                    // [cls_loss*2, link_loss]
  char* ws = (char*)d_ws;

  unsigned* hist1 = (unsigned*)(ws + HIST1_OFF);
  unsigned* hist2 = (unsigned*)(ws + HIST2_OFF);
  unsigned* uarr  = (unsigned*)(ws + UARR_OFF);
  float*    clsl  = (float*)(ws + CLSL_OFF);
  float*    clsw  = (float*)(ws + CLSW_OFF);
  unsigned* part  = (unsigned*)(ws + PART_OFF);
  unsigned* stats = (unsigned*)(ws + STATS_OFF);

  // Only the histograms accumulate via atomics -> only they need zeroing.
  hipMemsetAsync(hist1, 0, 8ull << 20, stream);   // hist1 + hist2 (contiguous)

  dim3 grid(NBLK), block(256);
  kA<<<grid, block, 0, stream>>>(target, logits, hist1, uarr, clsl, clsw, part);
  kRedScan1<<<20, 256, 0, stream>>>(part, hist1, stats);
  kC<<<grid, block, 0, stream>>>(uarr, hist2, stats);
  kScan2<<<BB, 256, 0, stream>>>(hist2, stats);
  kB<<<grid, block, 0, stream>>>(uarr, clsl, clsw, stats, part);
  kFinal<<<1, 256, 0, stream>>>(part, stats, out);
}

// Round 3
// 148.503 us; speedup vs baseline: 1.9236x; 1.0775x over previous
//
#include <hip/hip_runtime.h>
#include <math.h>

// Problem constants (fixed by setup_inputs)
#define BB   16
#define HW   65536          // 256*256
#define NPIX (BB * HW)      // 1,048,576
#define PBLK 1024           // blocks in per-pixel kernels (4 pixels/thread, 256 thr)

// ws layout (bytes)
#define HIST1_OFF 0ull            // 16*65536*4 = 4 MB
#define HIST2_OFF (4ull << 20)    // 4 MB
#define UARR_OFF  (8ull << 20)    // 4 MB
#define CLSL_OFF  (12ull << 20)   // 4 MB
// 9 partial arrays of PBLK floats (plain stores, no contended atomics):
//  0: pos count  1: neg count  2..5: s1,m1,s0,m0  6: sum(clsl*clsw)
//  7: sel count (kB)  8: sum(clsl over selected) (kB)
#define PART_OFF  (16ull << 20)
#define STATS_OFF (PART_OFF + 9ull * PBLK * 4ull)

// stats indices (u32 view unless noted) — every slot written, never accumulated
#define S_NPOS   0    // [16]
#define S_NNEG   16   // [16]
#define S_BUCKET 32   // [16] hi-16 bucket (0xFFFFFFFF = shortcut/skip)
#define S_RANK   48   // [16]
#define S_THR    64   // [16] select: u <= thr
#define F_S1     80   // float link sums (s1,m1,s0,m0)
#define F_WCL    84   // float sum(clsl*clsw) over ALL pixels

// monotone unsigned mapping of float bits (ascending float -> ascending uint)
__device__ __forceinline__ unsigned fmap(float x) {
  unsigned b = __float_as_uint(x);
  return (b & 0x80000000u) ? ~b : (b | 0x80000000u);
}

// log(1 + e^{-|d|}) with native exp/log: arg of log is in (1,2] -> accurate
__device__ __forceinline__ float softplus_neg_abs(float d) {
  return __logf(1.f + __expf(-fabsf(d)));
}

// Pass A: read both inputs once (16B loads, 4 pixels/thread); per-pixel
// records, hi-16 histogram, per-block partials via plain stores.
__global__ void kA(const float* __restrict__ target, const float* __restrict__ logits,
                   unsigned* __restrict__ hist1, unsigned* __restrict__ uarr,
                   float* __restrict__ clsl, float* __restrict__ part) {
  int tid = blockIdx.x * 256 + threadIdx.x;
  int p0 = tid * 4;                 // 4 consecutive pixels, same image
  int b = p0 >> 16;
  int hw = p0 & 65535;

  // target: 40 consecutive floats = 10 float4
  const float4* t4 = (const float4*)(target + (size_t)p0 * 10);
  float tf[40];
#pragma unroll
  for (int j = 0; j < 10; j++) {
    float4 v = t4[j];
    tf[4 * j] = v.x; tf[4 * j + 1] = v.y; tf[4 * j + 2] = v.z; tf[4 * j + 3] = v.w;
  }
  // logits: 10 channels x float4
  const float* lg = logits + (size_t)b * 10 * HW + hw;
  float lf[40];
#pragma unroll
  for (int c = 0; c < 10; c++) {
    float4 v = *(const float4*)(lg + (size_t)c * HW);
    lf[4 * c] = v.x; lf[4 * c + 1] = v.y; lf[4 * c + 2] = v.z; lf[4 * c + 3] = v.w;
  }

  float cpos = 0.f, cneg = 0.f, s1 = 0.f, m1 = 0.f, s0 = 0.f, m0 = 0.f, wcl = 0.f;
  float cl4[4];
  unsigned uu[4];
#pragma unroll
  for (int q = 0; q < 4; q++) {
    float label = tf[10 * q];
    float wgt   = tf[10 * q + 1];
    bool pos = label > 0.f;
    bool neg = label == 0.f;
    float l0 = lf[0 * 4 + q], l1 = lf[1 * 4 + q];
    float d = l0 - l1;
    float cl = fmaxf(l0, l1) + softplus_neg_abs(d) - (pos ? l1 : l0);
    cl4[q] = cl;
    wcl += cl * wgt;
    cpos += pos ? 1.f : 0.f;
    cneg += neg ? 1.f : 0.f;
    unsigned u = fmap(d);           // score = sigmoid(d) monotone in d
    uu[q] = neg ? u : 0xFFFFFFFFu;  // finite d never maps to 0xFFFFFFFF
    if (neg) atomicAdd(&hist1[(size_t)b * 65536 + (u >> 16)], 1u);
#pragma unroll
    for (int n = 0; n < 4; n++) {
      float a = lf[(2 + n) * 4 + q];   // class-0 logit
      float c = lf[(6 + n) * 4 + q];   // class-1 logit
      float ce0 = fmaxf(a, c) + softplus_neg_abs(a - c);
      int lab = (int)tf[10 * q + 2 + n];
      float ce = ce0 - (lab ? c : a);
      float w = tf[10 * q + 6 + n];
      if (lab) { m1 += w; s1 += w * ce; }
      else     { m0 += w; s0 += w * ce; }
    }
  }
  *(float4*)(clsl + p0) = make_float4(cl4[0], cl4[1], cl4[2], cl4[3]);
  *(uint4*)(uarr + p0)  = make_uint4(uu[0], uu[1], uu[2], uu[3]);

  // block reduction of 7 quantities -> per-block partial stores
  float vals[7] = {cpos, cneg, s1, m1, s0, m0, wcl};
  __shared__ float red[7][4];
  int lane = threadIdx.x & 63, wave = threadIdx.x >> 6;
#pragma unroll
  for (int q = 0; q < 7; q++) {
    float x = vals[q];
    for (int o = 32; o; o >>= 1) x += __shfl_down(x, o, 64);
    if (lane == 0) red[q][wave] = x;
  }
  __syncthreads();
  if (threadIdx.x < 7) {
    int q = threadIdx.x;
    part[(size_t)q * PBLK + blockIdx.x] = red[q][0] + red[q][1] + red[q][2] + red[q][3];
  }
}

// Blocks 0-15: reduce image b's 64 count-partials, then hi-16 radix scan.
// Blocks 16-20: reduce one PBLK-entry float partial array each (s1,m1,s0,m0,wcl).
__global__ void kRedScan1(const float* __restrict__ part, const unsigned* __restrict__ hist1,
                          unsigned* __restrict__ stats) {
  int lane = threadIdx.x & 63, wave = threadIdx.x >> 6;
  if (blockIdx.x >= 16) {
    int q = blockIdx.x - 16;                    // slot 2+q -> stats F_S1+q
    const float* p = part + (size_t)(2 + q) * PBLK;
    float s = 0.f;
    for (int t = threadIdx.x; t < PBLK; t += 256) s += p[t];
    for (int o = 32; o; o >>= 1) s += __shfl_down(s, o, 64);
    __shared__ float r[4];
    if (lane == 0) r[wave] = s;
    __syncthreads();
    if (threadIdx.x == 0) ((float*)stats)[F_S1 + q] = r[0] + r[1] + r[2] + r[3];
    return;
  }
  int b = blockIdx.x;
  // image b's kA blocks: [b*64, b*64+64)
  float cp = 0.f, cn = 0.f;
  if (threadIdx.x < 64) {
    cp = part[0 * PBLK + b * 64 + threadIdx.x];
    cn = part[1 * PBLK + b * 64 + threadIdx.x];
  }
  for (int o = 32; o; o >>= 1) { cp += __shfl_down(cp, o, 64); cn += __shfl_down(cn, o, 64); }
  __shared__ unsigned snpos, snneg;
  if (threadIdx.x == 0) {
    snpos = (unsigned)(cp + 0.5f);
    snneg = (unsigned)(cn + 0.5f);
    stats[S_NPOS + b] = snpos;
    stats[S_NNEG + b] = snneg;
  }
  __syncthreads();
  unsigned npos = snpos, nneg = snneg;
  unsigned k = min(3u * npos, nneg);
  if (npos == 0u || k == 0u || k >= nneg) {
    // use_all OR k==n_neg: select all negatives (non-neg pixels carry 0xFFFFFFFF)
    if (threadIdx.x == 0) { stats[S_THR + b] = 0xFFFFFFFEu; stats[S_BUCKET + b] = 0xFFFFFFFFu; }
    return;
  }
  __shared__ unsigned partl[256], pref[256];
  const unsigned* h = hist1 + (size_t)b * 65536 + (size_t)threadIdx.x * 256;
  unsigned p = 0;
  for (int j = 0; j < 256; j++) p += h[j];
  partl[threadIdx.x] = p;
  __syncthreads();
  if (threadIdx.x == 0) {
    unsigned c = 0;
    for (int t = 0; t < 256; t++) { pref[t] = c; c += partl[t]; }
  }
  __syncthreads();
  unsigned before = pref[threadIdx.x];
  if (before < k && k <= before + partl[threadIdx.x]) {   // exactly one thread
    unsigned cum = before;
    for (int j = 0; j < 256; j++) {
      unsigned cnt = h[j];
      if (k <= cum + cnt) {
        stats[S_BUCKET + b] = (unsigned)threadIdx.x * 256u + (unsigned)j;
        stats[S_RANK + b] = k - cum;
        break;
      }
      cum += cnt;
    }
  }
}

// lo-16 histogram within the selected bucket (skipped per-image via flag)
__global__ void kC(const unsigned* __restrict__ uarr, unsigned* __restrict__ hist2,
                   const unsigned* __restrict__ stats) {
  int b = blockIdx.x >> 6;                       // 64 blocks per image
  unsigned bk = stats[S_BUCKET + b];
  if (bk == 0xFFFFFFFFu) return;
  int p0 = (blockIdx.x * 256 + threadIdx.x) * 4;
  uint4 u4 = *(const uint4*)(uarr + p0);
  unsigned us[4] = {u4.x, u4.y, u4.z, u4.w};
#pragma unroll
  for (int q = 0; q < 4; q++) {
    unsigned u = us[q];
    if (u != 0xFFFFFFFFu && (u >> 16) == bk)
      atomicAdd(&hist2[(size_t)b * 65536 + (u & 0xFFFFu)], 1u);
  }
}

// lo-16 scan within the chosen bucket -> final threshold
__global__ void kScan2(const unsigned* __restrict__ hist2, unsigned* __restrict__ stats) {
  int b = blockIdx.x;
  unsigned bucket = stats[S_BUCKET + b];
  if (bucket == 0xFFFFFFFFu) return;
  unsigned k = stats[S_RANK + b];
  __shared__ unsigned partl[256], pref[256];
  const unsigned* h = hist2 + (size_t)b * 65536 + (size_t)threadIdx.x * 256;
  unsigned p = 0;
  for (int j = 0; j < 256; j++) p += h[j];
  partl[threadIdx.x] = p;
  __syncthreads();
  if (threadIdx.x == 0) {
    unsigned c = 0;
    for (int t = 0; t < 256; t++) { pref[t] = c; c += partl[t]; }
  }
  __syncthreads();
  unsigned before = pref[threadIdx.x];
  if (before < k && k <= before + partl[threadIdx.x]) {
    unsigned cum = before;
    for (int j = 0; j < 256; j++) {
      unsigned cnt = h[j];
      if (k <= cum + cnt) {
        stats[S_THR + b] = (bucket << 16) | ((unsigned)threadIdx.x * 256u + (unsigned)j);
        break;
      }
      cum += cnt;
    }
  }
}

// Final per-pixel pass: selection; per-block partial stores (count + sum clsl).
__global__ void kB(const unsigned* __restrict__ uarr, const float* __restrict__ clsl,
                   const unsigned* __restrict__ stats, float* __restrict__ part) {
  int tid = blockIdx.x * 256 + threadIdx.x;
  int p0 = tid * 4;
  int b = p0 >> 16;
  unsigned thr = stats[S_THR + b];
  uint4 u4 = *(const uint4*)(uarr + p0);
  float4 c4 = *(const float4*)(clsl + p0);
  float cnt = 0.f, sum = 0.f;
  if (u4.x <= thr) { cnt += 1.f; sum += c4.x; }
  if (u4.y <= thr) { cnt += 1.f; sum += c4.y; }
  if (u4.z <= thr) { cnt += 1.f; sum += c4.z; }
  if (u4.w <= thr) { cnt += 1.f; sum += c4.w; }
  for (int o = 32; o; o >>= 1) {
    cnt += __shfl_down(cnt, o, 64);
    sum += __shfl_down(sum, o, 64);
  }
  __shared__ float rc[4], rs[4];
  int lane = threadIdx.x & 63, wave = threadIdx.x >> 6;
  if (lane == 0) { rc[wave] = cnt; rs[wave] = sum; }
  __syncthreads();
  if (threadIdx.x == 0) {
    part[7 * PBLK + blockIdx.x] = rc[0] + rc[1] + rc[2] + rc[3];
    part[8 * PBLK + blockIdx.x] = rs[0] + rs[1] + rs[2] + rs[3];
  }
}

// Reduce kB's partials + assemble both outputs. One block.
__global__ void kFinal(const float* __restrict__ part, const unsigned* __restrict__ stats,
                       float* __restrict__ out) {
  float cnt = 0.f, sum = 0.f;
  for (int t = threadIdx.x; t < PBLK; t += 256) {
    cnt += part[7 * PBLK + t];
    sum += part[8 * PBLK + t];
  }
  for (int o = 32; o; o >>= 1) {
    cnt += __shfl_down(cnt, o, 64);
    sum += __shfl_down(sum, o, 64);
  }
  __shared__ float rc[4], rs[4];
  int lane = threadIdx.x & 63, wave = threadIdx.x >> 6;
  if (lane == 0) { rc[wave] = cnt; rs[wave] = sum; }
  __syncthreads();
  if (threadIdx.x == 0) {
    unsigned nsel = (unsigned)(rc[0] + rc[1] + rc[2] + rc[3] + 0.5f);
    float selsum = rs[0] + rs[1] + rs[2] + rs[3];
    unsigned npos = 0;
    for (int b = 0; b < BB; b++) npos += stats[S_NPOS + b];
    const float* f = (const float*)stats;
    out[0] = 2.f * (f[F_WCL] + selsum) / (float)(npos + nsel);
    out[1] = (npos != 0u) ? (f[F_S1 + 0] / f[F_S1 + 1] + f[F_S1 + 2] / f[F_S1 + 3]) : 0.f;
  }
}

extern "C" void kernel_launch(void* const* d_in, const int* in_sizes, int n_in,
                              void* d_out, int out_size, void* d_ws, size_t ws_size,
                              hipStream_t stream) {
  const float* target = (const float*)d_in[0];   // (16,256,256,10)
  const float* logits = (const float*)d_in[1];   // (16,10,256,256)
  float* out = (float*)d_out;                    // [cls_loss*2, link_loss]
  char* ws = (char*)d_ws;

  unsigned* hist1 = (unsigned*)(ws + HIST1_OFF);
  unsigned* hist2 = (unsigned*)(ws + HIST2_OFF);
  unsigned* uarr  = (unsigned*)(ws + UARR_OFF);
  float*    clsl  = (float*)(ws + CLSL_OFF);
  float*    part  = (float*)(ws + PART_OFF);
  unsigned* stats = (unsigned*)(ws + STATS_OFF);

  // Only the histograms accumulate via atomics -> only they need zeroing.
  hipMemsetAsync(hist1, 0, 8ull << 20, stream);   // hist1 + hist2 (contiguous)

  dim3 grid(PBLK), block(256);
  kA<<<grid, block, 0, stream>>>(target, logits, hist1, uarr, clsl, part);
  kRedScan1<<<21, 256, 0, stream>>>(part, hist1, stats);
  kC<<<grid, block, 0, stream>>>(uarr, hist2, stats);
  kScan2<<<BB, 256, 0, stream>>>(hist2, stats);
  kB<<<grid, block, 0, stream>>>(uarr, clsl, stats, part);
  kFinal<<<1, 256, 0, stream>>>(part, stats, out);
}